// Round 3
// baseline (655.661 us; speedup 1.0000x reference)
//
#include <hip/hip_runtime.h>

typedef __attribute__((ext_vector_type(8))) short bf16x8;
typedef __attribute__((ext_vector_type(4))) float f32x4;
typedef __attribute__((ext_vector_type(4))) unsigned short us4;

__device__ __forceinline__ unsigned short f2bf(float f) {
    unsigned u = __builtin_bit_cast(unsigned, f);
    u += 0x7FFFu + ((u >> 16) & 1u);
    return (unsigned short)(u >> 16);
}

__device__ __forceinline__ void gl_lds16(const void* g, void* l) {
    __builtin_amdgcn_global_load_lds(
        (const __attribute__((address_space(1))) unsigned int*)g,
        (__attribute__((address_space(3))) unsigned int*)l, 16, 0, 0);
}

// ---------------- cast fp32 -> bf16 (vectorized) ----------------
__global__ __launch_bounds__(256) void cast_f32_bf16(const float* __restrict__ in,
                                                     unsigned short* __restrict__ out, int n4) {
    int i = blockIdx.x * blockDim.x + threadIdx.x;
    int stride = gridDim.x * blockDim.x;
    for (; i < n4; i += stride) {
        float4 v = ((const float4*)in)[i];
        us4 o;
        o.x = f2bf(v.x); o.y = f2bf(v.y); o.z = f2bf(v.z); o.w = f2bf(v.w);
        ((us4*)out)[i] = o;
    }
}

// ---------------- weight transpose + cast: Wt[slot][n][k] = W[slot][k][n] ----------------
__global__ __launch_bounds__(256) void transpose_w(const float* __restrict__ wq,
                                                   const float* __restrict__ wk,
                                                   const float* __restrict__ wv,
                                                   const float* __restrict__ wp,
                                                   unsigned short* __restrict__ Wt) {
    int sb = blockIdx.x >> 6;     // slot 0..191
    int tile = blockIdx.x & 63;   // 8x8 tiles of 64x64
    const float* src;
    if (sb < 32)       src = wq + (size_t)sb * 262144;
    else if (sb < 96)  src = wk + (size_t)(sb - 32) * 262144;
    else if (sb < 160) src = wv + (size_t)(sb - 96) * 262144;
    else               src = wp + (size_t)(sb - 160) * 262144;
    unsigned short* dst = Wt + (size_t)sb * 262144;
    int q0 = (tile & 7) * 64, e0 = (tile >> 3) * 64;
    __shared__ float t[64][65];
    int tx = threadIdx.x & 63, ty = threadIdx.x >> 6;
    for (int i = 0; i < 16; i++) {
        int r = ty + 4 * i;
        t[r][tx] = src[(size_t)(q0 + r) * 512 + e0 + tx];
    }
    __syncthreads();
    int tx2 = threadIdx.x & 31, ty2 = threadIdx.x >> 5;
    for (int i = 0; i < 8; i++) {
        int e = ty2 + 8 * i;
        int qq = tx2 * 2;
        unsigned a = f2bf(t[qq][e]);
        unsigned bb = f2bf(t[qq + 1][e]);
        *(unsigned*)&dst[(size_t)(e0 + e) * 512 + q0 + qq] = a | (bb << 16);
    }
}

// ---------------- batched GEMM, depth-3 counted-vmcnt pipeline ----------------
// grid 10240 1D; XCD-chunked slot-major order; K/V slots adjacent (share A slab in L2)
__global__ __launch_bounds__(256, 1) void gemm_qkv(const unsigned short* __restrict__ qb,
                                                   const unsigned short* __restrict__ kb,
                                                   const unsigned short* __restrict__ Wt,
                                                   unsigned short* __restrict__ Qs,
                                                   unsigned short* __restrict__ Ks,
                                                   unsigned short* __restrict__ Vs) {
    __shared__ __align__(16) unsigned short lds[4][2][8192];  // 4 bufs x (A,B) x 128x64 = 128 KiB
    int bid = blockIdx.x;
    int logical = (bid & 7) * 1280 + (bid >> 3);   // bijective XCD chunking (10240 = 8*1280)
    int sIdx = logical >> 6, x = logical & 63;
    int tm = x >> 2, tn = x & 3;
    const unsigned short* A;
    unsigned short* Cw;
    int wslot;
    if (sIdx < 32) {                // Q slots first
        A = qb + (size_t)sIdx * 1048576; Cw = Qs + (size_t)sIdx * 1048576; wslot = sIdx;
    } else {                        // then K/V interleaved pairs sharing the kb slab
        int p = sIdx - 32, ks = p >> 1;
        A = kb + (size_t)ks * 1048576;
        if (p & 1) { Cw = Vs + (size_t)ks * 1048576; wslot = 96 + ks; }
        else       { Cw = Ks + (size_t)ks * 1048576; wslot = 32 + ks; }
    }
    const unsigned short* B = Wt + (size_t)wslot * 262144;
    int l = threadIdx.x & 63, w = threadIdx.x >> 6;
    const unsigned short* Ag = A + (size_t)(tm * 128) * 512;
    const unsigned short* Bg = B + (size_t)(tn * 128) * 512;
    int wr = (w >> 1) * 64, wc = (w & 1) * 64;
    int srcs = ((l & 7) ^ (l >> 3)) * 8;   // pre-swizzled source k-slot (XOR with row&7)

    f32x4 acc[4][4] = {};

#define STAGE(bufi, k0)                                                               \
    for (int p = 0; p < 4; p++) {                                                     \
        int row = w * 32 + p * 8 + (l >> 3);                                          \
        gl_lds16(Ag + (size_t)row * 512 + (k0) + srcs, &lds[bufi][0][(w*32+p*8)*64]); \
        gl_lds16(Bg + (size_t)row * 512 + (k0) + srcs, &lds[bufi][1][(w*32+p*8)*64]); \
    }

    STAGE(0, 0) STAGE(1, 64) STAGE(2, 128)      // 24 loads in flight
    asm volatile("s_waitcnt vmcnt(16)" ::: "memory");   // batch 0 landed
    __builtin_amdgcn_s_barrier();

#pragma unroll
    for (int t = 0; t < 8; t++) {
        if (t <= 4) { STAGE((t + 3) & 3, (t + 3) * 64) }   // prefetch batch t+3
        const unsigned short* la = &lds[t & 3][0][0];
        const unsigned short* lb = &lds[t & 3][1][0];
        bf16x8 aF[2][4], bF[2][4];
        for (int kc = 0; kc < 2; kc++) {
            int sp = ((kc * 4 + (l >> 4)) ^ (l & 7)) * 8;  // swizzled read slot
            for (int m = 0; m < 4; m++)
                aF[kc][m] = *(const bf16x8*)&la[(wr + m * 16 + (l & 15)) * 64 + sp];
            for (int n = 0; n < 4; n++)
                bF[kc][n] = *(const bf16x8*)&lb[(wc + n * 16 + (l & 15)) * 64 + sp];
        }
        __builtin_amdgcn_s_setprio(1);
        for (int kc = 0; kc < 2; kc++)
            for (int m = 0; m < 4; m++)
                for (int n = 0; n < 4; n++)
                    acc[m][n] = __builtin_amdgcn_mfma_f32_16x16x32_bf16(aF[kc][m], bF[kc][n], acc[m][n], 0, 0, 0);
        __builtin_amdgcn_s_setprio(0);
        // certify batch t+1 before crossing the barrier (vmcnt BEFORE barrier: all waves certified)
        if (t <= 4)      asm volatile("s_waitcnt vmcnt(16)" ::: "memory");
        else if (t == 5) asm volatile("s_waitcnt vmcnt(8)" ::: "memory");
        else if (t == 6) asm volatile("s_waitcnt vmcnt(0)" ::: "memory");
        if (t < 7) __builtin_amdgcn_s_barrier();
    }
#undef STAGE

    // epilogue: stage C-tile bf16 in LDS, emit full-line coalesced stores
    __syncthreads();
    unsigned short* Cs = &lds[0][0][0];  // [128][136]
    for (int m = 0; m < 4; m++)
        for (int n = 0; n < 4; n++)
            for (int r = 0; r < 4; r++)
                Cs[(wr + m * 16 + (l >> 4) * 4 + r) * 136 + wc + n * 16 + (l & 15)] = f2bf(acc[m][n][r]);
    __syncthreads();
    for (int rnd = 0; rnd < 8; rnd++) {
        int row = rnd * 16 + (threadIdx.x >> 4);
        int c8 = (threadIdx.x & 15) * 8;
        bf16x8 v = *(const bf16x8*)&Cs[row * 136 + c8];
        *(bf16x8*)&Cw[(size_t)(tm * 128 + row) * 512 + tn * 128 + c8] = v;
    }
}

// ---------------- final projection GEMM: out[slot][2048][512] fp32, same pipeline ----------------
__global__ __launch_bounds__(256, 1) void gemm_proj(const unsigned short* __restrict__ Ain,
                                                    const unsigned short* __restrict__ Wt,
                                                    float* __restrict__ out) {
    __shared__ __align__(16) unsigned short lds[4][2][8192];
    int bid = blockIdx.x;
    int logical = (bid & 7) * 256 + (bid >> 3);    // 2048 = 8*256
    int s = logical >> 6, x = logical & 63;
    int tm = x >> 2, tn = x & 3;
    const unsigned short* A = Ain + (size_t)s * 1048576;
    const unsigned short* B = Wt + (size_t)(160 + s) * 262144;
    int l = threadIdx.x & 63, w = threadIdx.x >> 6;
    const unsigned short* Ag = A + (size_t)(tm * 128) * 512;
    const unsigned short* Bg = B + (size_t)(tn * 128) * 512;
    int wr = (w >> 1) * 64, wc = (w & 1) * 64;
    int srcs = ((l & 7) ^ (l >> 3)) * 8;

    f32x4 acc[4][4] = {};

#define STAGE(bufi, k0)                                                               \
    for (int p = 0; p < 4; p++) {                                                     \
        int row = w * 32 + p * 8 + (l >> 3);                                          \
        gl_lds16(Ag + (size_t)row * 512 + (k0) + srcs, &lds[bufi][0][(w*32+p*8)*64]); \
        gl_lds16(Bg + (size_t)row * 512 + (k0) + srcs, &lds[bufi][1][(w*32+p*8)*64]); \
    }

    STAGE(0, 0) STAGE(1, 64) STAGE(2, 128)
    asm volatile("s_waitcnt vmcnt(16)" ::: "memory");
    __builtin_amdgcn_s_barrier();

#pragma unroll
    for (int t = 0; t < 8; t++) {
        if (t <= 4) { STAGE((t + 3) & 3, (t + 3) * 64) }
        const unsigned short* la = &lds[t & 3][0][0];
        const unsigned short* lb = &lds[t & 3][1][0];
        bf16x8 aF[2][4], bF[2][4];
        for (int kc = 0; kc < 2; kc++) {
            int sp = ((kc * 4 + (l >> 4)) ^ (l & 7)) * 8;
            for (int m = 0; m < 4; m++)
                aF[kc][m] = *(const bf16x8*)&la[(wr + m * 16 + (l & 15)) * 64 + sp];
            for (int n = 0; n < 4; n++)
                bF[kc][n] = *(const bf16x8*)&lb[(wc + n * 16 + (l & 15)) * 64 + sp];
        }
        __builtin_amdgcn_s_setprio(1);
        for (int kc = 0; kc < 2; kc++)
            for (int m = 0; m < 4; m++)
                for (int n = 0; n < 4; n++)
                    acc[m][n] = __builtin_amdgcn_mfma_f32_16x16x32_bf16(aF[kc][m], bF[kc][n], acc[m][n], 0, 0, 0);
        __builtin_amdgcn_s_setprio(0);
        if (t <= 4)      asm volatile("s_waitcnt vmcnt(16)" ::: "memory");
        else if (t == 5) asm volatile("s_waitcnt vmcnt(8)" ::: "memory");
        else if (t == 6) asm volatile("s_waitcnt vmcnt(0)" ::: "memory");
        if (t < 7) __builtin_amdgcn_s_barrier();
    }
#undef STAGE

    // epilogue: two half-tile fp32 passes through LDS, full 512B-row stores
    __syncthreads();
    float* Cf = (float*)&lds[0][0][0];  // [64][132]
    for (int pass = 0; pass < 2; pass++) {
        if (wr == pass * 64) {
            for (int m = 0; m < 4; m++)
                for (int n = 0; n < 4; n++)
                    for (int r = 0; r < 4; r++)
                        Cf[(m * 16 + (l >> 4) * 4 + r) * 132 + wc + n * 16 + (l & 15)] = acc[m][n][r];
        }
        __syncthreads();
        for (int rnd = 0; rnd < 8; rnd++) {
            int row = rnd * 8 + (threadIdx.x >> 5);
            int c4 = (threadIdx.x & 31) * 4;
            float4 v = *(const float4*)&Cf[row * 132 + c4];
            *(float4*)&out[(size_t)s * 1048576 + (size_t)(tm * 128 + pass * 64 + row) * 512 + tn * 128 + c4] = v;
        }
        __syncthreads();
    }
}

// ---------------- attention core: one wave per (b,h), slot-major inputs ----------------
__global__ __launch_bounds__(256) void attn_k(const unsigned short* __restrict__ Qs,
                                              const unsigned short* __restrict__ Ks,
                                              const unsigned short* __restrict__ Vs,
                                              unsigned short* __restrict__ Aout) {
    __shared__ __align__(16) unsigned short pl[4][32 * 72];
    __shared__ __align__(16) unsigned short vt[4][64 * 88];
    const size_t SL = 1048576;  // slot stride (elems)
    int w = threadIdx.x >> 6, l = threadIdx.x & 63;
    int g = blockIdx.x * 4 + w;
    int b = g >> 3, h = g & 7;
    const unsigned short* Qp = Qs + (size_t)b * 512 + h * 64;
    const unsigned short* Kp = Ks + (size_t)b * 512 + h * 64;
    const unsigned short* Vp = Vs + (size_t)b * 512 + h * 64;
    int lr = l & 15, lc = l >> 4;
    unsigned short* vtw = vt[w];

    // stage V^T [d][j] into LDS
    for (int jr = 0; jr < 64; jr += 8) {
        int j = jr + (l >> 3), d0 = (l & 7) * 8;
        bf16x8 v = *(const bf16x8*)&Vp[(size_t)j * SL + d0];
        for (int e = 0; e < 8; e++) vtw[(d0 + e) * 88 + j] = (unsigned short)v[e];
    }

    bf16x8 aQ[2][2], bK[4][2];
    for (int m = 0; m < 2; m++)
        for (int kc = 0; kc < 2; kc++)
            aQ[m][kc] = *(const bf16x8*)&Qp[(size_t)(m * 16 + lr) * SL + kc * 32 + lc * 8];
    for (int n = 0; n < 4; n++)
        for (int kc = 0; kc < 2; kc++)
            bK[n][kc] = *(const bf16x8*)&Kp[(size_t)(n * 16 + lr) * SL + kc * 32 + lc * 8];

    f32x4 acc[2][4] = {};
    for (int kc = 0; kc < 2; kc++)
        for (int m = 0; m < 2; m++)
            for (int n = 0; n < 4; n++)
                acc[m][n] = __builtin_amdgcn_mfma_f32_16x16x32_bf16(aQ[m][kc], bK[n][kc], acc[m][n], 0, 0, 0);

    const float sc = 0.18033688011112042f;  // log2(e)/8
    for (int m = 0; m < 2; m++) {
        for (int r = 0; r < 4; r++) {
            float v = acc[m][0][r];
            for (int n = 1; n < 4; n++) v = fmaxf(v, acc[m][n][r]);
            for (int sh = 1; sh < 16; sh <<= 1) v = fmaxf(v, __shfl_xor(v, sh));
            float ssum = 0.f;
            for (int n = 0; n < 4; n++) {
                float p = exp2f((acc[m][n][r] - v) * sc);
                acc[m][n][r] = p;
                ssum += p;
            }
            for (int sh = 1; sh < 16; sh <<= 1) ssum += __shfl_xor(ssum, sh);
            float inv = 1.0f / ssum;
            for (int n = 0; n < 4; n++)
                pl[w][(m * 16 + lc * 4 + r) * 72 + n * 16 + lr] = f2bf(acc[m][n][r] * inv);
        }
    }

    bf16x8 aP[2][2], bV[4][2];
    for (int m = 0; m < 2; m++)
        for (int kc = 0; kc < 2; kc++)
            aP[m][kc] = *(const bf16x8*)&pl[w][(m * 16 + lr) * 72 + kc * 32 + lc * 8];
    for (int n = 0; n < 4; n++)
        for (int kc = 0; kc < 2; kc++)
            bV[n][kc] = *(const bf16x8*)&vtw[(n * 16 + lr) * 88 + kc * 32 + lc * 8];

    f32x4 o[2][4] = {};
    for (int kc = 0; kc < 2; kc++)
        for (int m = 0; m < 2; m++)
            for (int n = 0; n < 4; n++)
                o[m][n] = __builtin_amdgcn_mfma_f32_16x16x32_bf16(aP[m][kc], bV[n][kc], o[m][n], 0, 0, 0);

    // stage O per-wave in LDS (reuse vtw), write full-line 128B rows
    for (int m = 0; m < 2; m++)
        for (int n = 0; n < 4; n++)
            for (int r = 0; r < 4; r++)
                vtw[(m * 16 + lc * 4 + r) * 88 + n * 16 + lr] = f2bf(o[m][n][r]);
    for (int rnd = 0; rnd < 4; rnd++) {
        int i = rnd * 8 + (l >> 3), d0 = (l & 7) * 8;
        bf16x8 v = *(const bf16x8*)&vtw[i * 88 + d0];
        *(bf16x8*)&Aout[(size_t)i * SL + (size_t)b * 512 + h * 64 + d0] = v;
    }
}

extern "C" void kernel_launch(void* const* d_in, const int* in_sizes, int n_in,
                              void* d_out, int out_size, void* d_ws, size_t ws_size,
                              hipStream_t stream) {
    const float* q  = (const float*)d_in[0];
    const float* k  = (const float*)d_in[1];
    const float* wq = (const float*)d_in[2];
    const float* wk = (const float*)d_in[3];
    const float* wv = (const float*)d_in[4];
    const float* wp = (const float*)d_in[5];

    char* ws = (char*)d_ws;
    unsigned short* qb = (unsigned short*)(ws);                          // 64 MiB
    unsigned short* kb = (unsigned short*)(ws + ((size_t)64 << 20));     // 128 MiB
    unsigned short* Wt = (unsigned short*)(ws + ((size_t)192 << 20));    // 96 MiB
    unsigned short* Qs = (unsigned short*)(ws + ((size_t)288 << 20));    // 64 MiB
    unsigned short* Ks = (unsigned short*)(ws + ((size_t)352 << 20));    // 128 MiB
    unsigned short* Vs = (unsigned short*)(ws + ((size_t)480 << 20));    // 128 MiB
    unsigned short* Aout = qb;  // reuse: qb dead after gemm_qkv
    float* out = (float*)d_out;

    hipLaunchKernelGGL(cast_f32_bf16, dim3(2048), dim3(256), 0, stream, q, qb, 32 * 2048 * 512 / 4);
    hipLaunchKernelGGL(cast_f32_bf16, dim3(2048), dim3(256), 0, stream, k, kb, 64 * 2048 * 512 / 4);
    hipLaunchKernelGGL(transpose_w, dim3(192 * 64), dim3(256), 0, stream, wq, wk, wv, wp, Wt);
    hipLaunchKernelGGL(gemm_qkv, dim3(10240), dim3(256), 0, stream, qb, kb, Wt, Qs, Ks, Vs);
    hipLaunchKernelGGL(attn_k, dim3(4096), dim3(256), 0, stream, Qs, Ks, Vs, Aout);
    hipLaunchKernelGGL(gemm_proj, dim3(2048), dim3(256), 0, stream, Aout, Wt, out);
}

// Round 5
// 551.723 us; speedup vs baseline: 1.1884x; 1.1884x over previous
//
#include <hip/hip_runtime.h>

typedef __attribute__((ext_vector_type(8))) short bf16x8;
typedef __attribute__((ext_vector_type(4))) float f32x4;
typedef __attribute__((ext_vector_type(4))) unsigned short us4;

__device__ __forceinline__ unsigned short f2bf(float f) {
    unsigned u = __builtin_bit_cast(unsigned, f);
    u += 0x7FFFu + ((u >> 16) & 1u);
    return (unsigned short)(u >> 16);
}

__device__ __forceinline__ void gl_lds16(const void* g, void* l) {
    __builtin_amdgcn_global_load_lds(
        (const __attribute__((address_space(1))) unsigned int*)g,
        (__attribute__((address_space(3))) unsigned int*)l, 16, 0, 0);
}

// ---------------- cast fp32 -> bf16 (vectorized) ----------------
__global__ __launch_bounds__(256) void cast_f32_bf16(const float* __restrict__ in,
                                                     unsigned short* __restrict__ out, int n4) {
    int i = blockIdx.x * blockDim.x + threadIdx.x;
    int stride = gridDim.x * blockDim.x;
    for (; i < n4; i += stride) {
        float4 v = ((const float4*)in)[i];
        us4 o;
        o.x = f2bf(v.x); o.y = f2bf(v.y); o.z = f2bf(v.z); o.w = f2bf(v.w);
        ((us4*)out)[i] = o;
    }
}

// ---------------- weight transpose + cast: Wt[slot][n][k] = W[slot][k][n] ----------------
__global__ __launch_bounds__(256) void transpose_w(const float* __restrict__ wq,
                                                   const float* __restrict__ wk,
                                                   const float* __restrict__ wv,
                                                   const float* __restrict__ wp,
                                                   unsigned short* __restrict__ Wt) {
    int sb = blockIdx.x >> 6;
    int tile = blockIdx.x & 63;
    const float* src;
    if (sb < 32)       src = wq + (size_t)sb * 262144;
    else if (sb < 96)  src = wk + (size_t)(sb - 32) * 262144;
    else if (sb < 160) src = wv + (size_t)(sb - 96) * 262144;
    else               src = wp + (size_t)(sb - 160) * 262144;
    unsigned short* dst = Wt + (size_t)sb * 262144;
    int q0 = (tile & 7) * 64, e0 = (tile >> 3) * 64;
    __shared__ float t[64][65];
    int tx = threadIdx.x & 63, ty = threadIdx.x >> 6;
    for (int i = 0; i < 16; i++) {
        int r = ty + 4 * i;
        t[r][tx] = src[(size_t)(q0 + r) * 512 + e0 + tx];
    }
    __syncthreads();
    int tx2 = threadIdx.x & 31, ty2 = threadIdx.x >> 5;
    for (int i = 0; i < 8; i++) {
        int e = ty2 + 8 * i;
        int qq = tx2 * 2;
        unsigned a = f2bf(t[qq][e]);
        unsigned bb = f2bf(t[qq + 1][e]);
        *(unsigned*)&dst[(size_t)(e0 + e) * 512 + q0 + qq] = a | (bb << 16);
    }
}

// ---------------- 256x256x(K=512) 8-phase MFMA body (T2+T3+T4+T5) ----------------
// 512 threads = 8 waves (2M x 4N); per-wave C: 128x64 = acc[8][4].
// LDS: 2 bufs x {A 256x64, B 256x64} bf16 = 128 KiB. XOR-swizzled k-slots.
// Staging: 1 half-tile (128 rows, 2 gload_lds/wave) per phase; vmcnt(4) twice/iter.
__device__ __forceinline__ void gemm256(const unsigned short* __restrict__ Ag,
                                        const unsigned short* __restrict__ Bg,
                                        unsigned short (&lds)[2][2][16384],
                                        f32x4 (&acc)[8][4]) {
    const int tid = threadIdx.x;
    const int l = tid & 63, wid = tid >> 6;
    const int wr = (wid >> 2) * 128, wc = (wid & 3) * 64;
    const int lr = l & 15, shi = l >> 4;
    const int srcs = ((l & 7) ^ ((l >> 3) & 7)) * 8;  // pre-swizzled global k-slot
    const int grow = l >> 3;

    bf16x8 af[4][2], bf[2][2][2];

#define STG_(which, hh, t) do {                                                     \
    const unsigned short* gp = (which) ? Bg : Ag;                                   \
    _Pragma("unroll")                                                               \
    for (int q = 0; q < 2; q++) {                                                   \
        int lrow = (hh) * 128 + wid * 16 + q * 8;                                   \
        gl_lds16(gp + (size_t)(lrow + grow) * 512 + (t) * 64 + srcs,                \
                 &lds[(t) & 1][which][lrow * 64]);                                  \
    } } while (0)

#define LDA_(cur, mh) do {                                                          \
    _Pragma("unroll") for (int m = 0; m < 4; m++)                                   \
    _Pragma("unroll") for (int ks = 0; ks < 2; ks++)                                \
        af[m][ks] = *(const bf16x8*)&lds[cur][0]                                    \
            [(wr + (mh) * 64 + m * 16 + lr) * 64 + ((ks * 4 + shi) ^ (l & 7)) * 8]; \
    } while (0)

#define LDB_(cur, nh) do {                                                          \
    _Pragma("unroll") for (int n = 0; n < 2; n++)                                   \
    _Pragma("unroll") for (int ks = 0; ks < 2; ks++)                                \
        bf[nh][n][ks] = *(const bf16x8*)&lds[cur][1]                                \
            [(wc + (nh) * 32 + n * 16 + lr) * 64 + ((ks * 4 + shi) ^ (l & 7)) * 8]; \
    } while (0)

#define MM_(mh, nh) do {                                                            \
    __builtin_amdgcn_s_setprio(1);                                                  \
    _Pragma("unroll") for (int m = 0; m < 4; m++)                                   \
    _Pragma("unroll") for (int n = 0; n < 2; n++)                                   \
    _Pragma("unroll") for (int ks = 0; ks < 2; ks++)                                \
        acc[(mh) * 4 + m][(nh) * 2 + n] = __builtin_amdgcn_mfma_f32_16x16x32_bf16(  \
            af[m][ks], bf[nh][n][ks], acc[(mh) * 4 + m][(nh) * 2 + n], 0, 0, 0);    \
    __builtin_amdgcn_s_setprio(0);                                                  \
    } while (0)

#define FENCE_ asm volatile("" ::: "memory")
#define BAR_ do { FENCE_; __builtin_amdgcn_s_barrier(); FENCE_; } while (0)

    // prologue: tile0 (A0,A1,B0,B1) + tile1 (B0,B1); certify tile0, leave t1B in flight
    STG_(0, 0, 0); STG_(0, 1, 0); STG_(1, 0, 0); STG_(1, 1, 0);
    STG_(1, 0, 1); STG_(1, 1, 1);
    asm volatile("s_waitcnt vmcnt(4)" ::: "memory");
    BAR_;

#pragma unroll
    for (int i = 0; i < 4; i++) {
        // ph0: quad (0,0) of tile 2i (buf0); stage A-h0 of tile 2i+1 -> buf1
        LDA_(0, 0); LDB_(0, 0);
        STG_(0, 0, 2 * i + 1);
        BAR_; MM_(0, 0); BAR_;
        // ph1: quad (0,1); stage A-h1 of tile 2i+1
        LDB_(0, 1);
        STG_(0, 1, 2 * i + 1);
        BAR_; MM_(0, 1); BAR_;
        // ph2: quad (1,0); stage B-h0 of tile 2i+2 -> buf0 (B reads done after ph1)
        LDA_(0, 1);
        if (i < 3) STG_(1, 0, 2 * i + 2);
        BAR_; MM_(1, 0); BAR_;
        // ph3: quad (1,1); stage B-h1 of tile 2i+2; certify tile 2i+1 before buf1 reads
        if (i < 3) STG_(1, 1, 2 * i + 2);
        BAR_; MM_(1, 1);
        if (i < 3) asm volatile("s_waitcnt vmcnt(4)" ::: "memory");
        else       asm volatile("s_waitcnt vmcnt(0)" ::: "memory");
        BAR_;
        // ph4: quad (0,0) of tile 2i+1 (buf1); stage A-h0 of tile 2i+2 (A reads done after ph2)
        LDA_(1, 0); LDB_(1, 0);
        if (i < 3) STG_(0, 0, 2 * i + 2);
        BAR_; MM_(0, 0); BAR_;
        // ph5: quad (0,1); stage A-h1 of tile 2i+2
        LDB_(1, 1);
        if (i < 3) STG_(0, 1, 2 * i + 2);
        BAR_; MM_(0, 1); BAR_;
        // ph6: quad (1,0); stage B-h0 of tile 2i+3 -> buf1 (buf1 B reads done after ph5)
        LDA_(1, 1);
        if (i <= 2) STG_(1, 0, 2 * i + 3);
        BAR_; MM_(1, 0); BAR_;
        // ph7: quad (1,1); stage B-h1 of tile 2i+3; certify tile 2i+2 before buf0 reads
        if (i <= 2) STG_(1, 1, 2 * i + 3);
        BAR_; MM_(1, 1);
        if (i < 3) asm volatile("s_waitcnt vmcnt(4)" ::: "memory");
        else       asm volatile("s_waitcnt vmcnt(0)" ::: "memory");
        BAR_;
    }
#undef STG_
#undef LDA_
#undef LDB_
#undef MM_
}

// ---------------- batched QKV GEMM: 160 slot-GEMMs, 16 blocks/slot ----------------
__global__ __launch_bounds__(512, 1) void gemm_qkv(const unsigned short* __restrict__ qb,
                                                   const unsigned short* __restrict__ kb,
                                                   const unsigned short* __restrict__ Wt,
                                                   unsigned short* __restrict__ Qs,
                                                   unsigned short* __restrict__ Ks,
                                                   unsigned short* __restrict__ Vs) {
    __shared__ __align__(16) unsigned short lds[2][2][16384];
    int bid = blockIdx.x;
    int logical = (bid & 7) * 320 + (bid >> 3);   // 2560 = 8*320, whole slots per XCD
    int sIdx = logical >> 4, x = logical & 15;
    int tm = x >> 1, tn = x & 1;
    const unsigned short* A;
    unsigned short* Cw;
    int wslot;
    if (sIdx < 32) {
        A = qb + (size_t)sIdx * 1048576; Cw = Qs + (size_t)sIdx * 1048576; wslot = sIdx;
    } else {                              // K/V pairs share the kb slab in L2
        int p = sIdx - 32, ks = p >> 1;
        A = kb + (size_t)ks * 1048576;
        if (p & 1) { Cw = Vs + (size_t)ks * 1048576; wslot = 96 + ks; }
        else       { Cw = Ks + (size_t)ks * 1048576; wslot = 32 + ks; }
    }
    const unsigned short* B = Wt + (size_t)wslot * 262144;
    const unsigned short* Ag = A + (size_t)(tm * 256) * 512;
    const unsigned short* Bg = B + (size_t)(tn * 256) * 512;

    f32x4 acc[8][4] = {};
    gemm256(Ag, Bg, lds, acc);

    // epilogue: 2 passes of 128 rows through LDS, full-line bf16 stores
    const int l = threadIdx.x & 63, wid = threadIdx.x >> 6;
    const int wm = wid >> 2, wc = (wid & 3) * 64;
    unsigned short* Cs = &lds[0][0][0];   // [128][264]
    for (int pass = 0; pass < 2; pass++) {
        __syncthreads();
        if (wm == pass) {
            for (int m = 0; m < 8; m++)
                for (int n = 0; n < 4; n++)
                    for (int r = 0; r < 4; r++)
                        Cs[(m * 16 + (l >> 4) * 4 + r) * 264 + wc + n * 16 + (l & 15)] = f2bf(acc[m][n][r]);
        }
        __syncthreads();
        for (int rnd = 0; rnd < 8; rnd++) {
            int idx = rnd * 512 + threadIdx.x;
            int row = idx >> 5, c8 = (idx & 31) * 8;
            bf16x8 v = *(const bf16x8*)&Cs[row * 264 + c8];
            *(bf16x8*)&Cw[(size_t)(tm * 256 + pass * 128 + row) * 512 + tn * 256 + c8] = v;
        }
    }
}

// ---------------- final projection GEMM: out[slot][2048][512] fp32 ----------------
__global__ __launch_bounds__(512, 1) void gemm_proj(const unsigned short* __restrict__ Ain,
                                                    const unsigned short* __restrict__ Wt,
                                                    float* __restrict__ out) {
    __shared__ __align__(16) unsigned short lds[2][2][16384];
    int bid = blockIdx.x;
    int logical = (bid & 7) * 64 + (bid >> 3);    // 512 = 8*64
    int s = logical >> 4, x = logical & 15;
    int tm = x >> 1, tn = x & 1;
    const unsigned short* A = Ain + (size_t)s * 1048576;
    const unsigned short* B = Wt + (size_t)(160 + s) * 262144;
    const unsigned short* Ag = A + (size_t)(tm * 256) * 512;
    const unsigned short* Bg = B + (size_t)(tn * 256) * 512;

    f32x4 acc[8][4] = {};
    gemm256(Ag, Bg, lds, acc);

    // epilogue: 4 passes of 64 rows fp32 through LDS, full-line stores
    const int l = threadIdx.x & 63, wid = threadIdx.x >> 6;
    const int wm = wid >> 2, wc = (wid & 3) * 64;
    float* Cf = (float*)&lds[0][0][0];    // [64][260]
    for (int pass = 0; pass < 4; pass++) {
        __syncthreads();
        if (wm == (pass >> 1)) {
            int mb = (pass & 1) * 4;
            for (int mm = 0; mm < 4; mm++)
                for (int n = 0; n < 4; n++)
                    for (int r = 0; r < 4; r++)
                        Cf[(mm * 16 + (l >> 4) * 4 + r) * 260 + wc + n * 16 + (l & 15)] = acc[mb + mm][n][r];
        }
        __syncthreads();
        for (int rnd = 0; rnd < 8; rnd++) {    // 64 rows x 256 cols fp32 = 8 rnds of 512x float4
            int idx = rnd * 512 + threadIdx.x;
            int row = idx >> 6, c4 = (idx & 63) * 4;
            float4 v = *(const float4*)&Cf[row * 260 + c4];
            *(float4*)&out[(size_t)s * 1048576 + (size_t)(tm * 256 + pass * 64 + row) * 512 + tn * 256 + c4] = v;
        }
    }
}

// ---------------- attention core: one wave per (b,h), slot-major inputs ----------------
__global__ __launch_bounds__(256) void attn_k(const unsigned short* __restrict__ Qs,
                                              const unsigned short* __restrict__ Ks,
                                              const unsigned short* __restrict__ Vs,
                                              unsigned short* __restrict__ Aout) {
    __shared__ __align__(16) unsigned short pl[4][32 * 72];
    __shared__ __align__(16) unsigned short vt[4][64 * 88];
    const size_t SL = 1048576;
    int w = threadIdx.x >> 6, l = threadIdx.x & 63;
    int g = blockIdx.x * 4 + w;
    int b = g >> 3, h = g & 7;
    const unsigned short* Qp = Qs + (size_t)b * 512 + h * 64;
    const unsigned short* Kp = Ks + (size_t)b * 512 + h * 64;
    const unsigned short* Vp = Vs + (size_t)b * 512 + h * 64;
    int lr = l & 15, lc = l >> 4;
    unsigned short* vtw = vt[w];

    for (int jr = 0; jr < 64; jr += 8) {
        int j = jr + (l >> 3), d0 = (l & 7) * 8;
        bf16x8 v = *(const bf16x8*)&Vp[(size_t)j * SL + d0];
        for (int e = 0; e < 8; e++) vtw[(d0 + e) * 88 + j] = (unsigned short)v[e];
    }

    bf16x8 aQ[2][2], bK[4][2];
    for (int m = 0; m < 2; m++)
        for (int kc = 0; kc < 2; kc++)
            aQ[m][kc] = *(const bf16x8*)&Qp[(size_t)(m * 16 + lr) * SL + kc * 32 + lc * 8];
    for (int n = 0; n < 4; n++)
        for (int kc = 0; kc < 2; kc++)
            bK[n][kc] = *(const bf16x8*)&Kp[(size_t)(n * 16 + lr) * SL + kc * 32 + lc * 8];

    f32x4 acc[2][4] = {};
    for (int kc = 0; kc < 2; kc++)
        for (int m = 0; m < 2; m++)
            for (int n = 0; n < 4; n++)
                acc[m][n] = __builtin_amdgcn_mfma_f32_16x16x32_bf16(aQ[m][kc], bK[n][kc], acc[m][n], 0, 0, 0);

    const float sc = 0.18033688011112042f;  // log2(e)/8
    for (int m = 0; m < 2; m++) {
        for (int r = 0; r < 4; r++) {
            float v = acc[m][0][r];
            for (int n = 1; n < 4; n++) v = fmaxf(v, acc[m][n][r]);
            for (int sh = 1; sh < 16; sh <<= 1) v = fmaxf(v, __shfl_xor(v, sh));
            float ssum = 0.f;
            for (int n = 0; n < 4; n++) {
                float p = exp2f((acc[m][n][r] - v) * sc);
                acc[m][n][r] = p;
                ssum += p;
            }
            for (int sh = 1; sh < 16; sh <<= 1) ssum += __shfl_xor(ssum, sh);
            float inv = 1.0f / ssum;
            for (int n = 0; n < 4; n++)
                pl[w][(m * 16 + lc * 4 + r) * 72 + n * 16 + lr] = f2bf(acc[m][n][r] * inv);
        }
    }

    bf16x8 aP[2][2], bV[4][2];
    for (int m = 0; m < 2; m++)
        for (int kc = 0; kc < 2; kc++)
            aP[m][kc] = *(const bf16x8*)&pl[w][(m * 16 + lr) * 72 + kc * 32 + lc * 8];
    for (int n = 0; n < 4; n++)
        for (int kc = 0; kc < 2; kc++)
            bV[n][kc] = *(const bf16x8*)&vtw[(n * 16 + lr) * 88 + kc * 32 + lc * 8];

    f32x4 o[2][4] = {};
    for (int kc = 0; kc < 2; kc++)
        for (int m = 0; m < 2; m++)
            for (int n = 0; n < 4; n++)
                o[m][n] = __builtin_amdgcn_mfma_f32_16x16x32_bf16(aP[m][kc], bV[n][kc], o[m][n], 0, 0, 0);

    for (int m = 0; m < 2; m++)
        for (int n = 0; n < 4; n++)
            for (int r = 0; r < 4; r++)
                vtw[(m * 16 + lc * 4 + r) * 88 + n * 16 + lr] = f2bf(o[m][n][r]);
    for (int rnd = 0; rnd < 4; rnd++) {
        int i = rnd * 8 + (l >> 3), d0 = (l & 7) * 8;
        bf16x8 v = *(const bf16x8*)&vtw[i * 88 + d0];
        *(bf16x8*)&Aout[(size_t)i * SL + (size_t)b * 512 + h * 64 + d0] = v;
    }
}

extern "C" void kernel_launch(void* const* d_in, const int* in_sizes, int n_in,
                              void* d_out, int out_size, void* d_ws, size_t ws_size,
                              hipStream_t stream) {
    const float* q  = (const float*)d_in[0];
    const float* k  = (const float*)d_in[1];
    const float* wq = (const float*)d_in[2];
    const float* wk = (const float*)d_in[3];
    const float* wv = (const float*)d_in[4];
    const float* wp = (const float*)d_in[5];

    char* ws = (char*)d_ws;
    unsigned short* qb = (unsigned short*)(ws);
    unsigned short* kb = (unsigned short*)(ws + ((size_t)64 << 20));
    unsigned short* Wt = (unsigned short*)(ws + ((size_t)192 << 20));
    unsigned short* Qs = (unsigned short*)(ws + ((size_t)288 << 20));
    unsigned short* Ks = (unsigned short*)(ws + ((size_t)352 << 20));
    unsigned short* Vs = (unsigned short*)(ws + ((size_t)480 << 20));
    unsigned short* Aout = qb;  // reuse: qb dead after gemm_qkv
    float* out = (float*)d_out;

    hipLaunchKernelGGL(cast_f32_bf16, dim3(2048), dim3(256), 0, stream, q, qb, 32 * 2048 * 512 / 4);
    hipLaunchKernelGGL(cast_f32_bf16, dim3(2048), dim3(256), 0, stream, k, kb, 64 * 2048 * 512 / 4);
    hipLaunchKernelGGL(transpose_w, dim3(192 * 64), dim3(256), 0, stream, wq, wk, wv, wp, Wt);
    hipLaunchKernelGGL(gemm_qkv, dim3(2560), dim3(512), 0, stream, qb, kb, Wt, Qs, Ks, Vs);
    hipLaunchKernelGGL(attn_k, dim3(4096), dim3(256), 0, stream, Qs, Ks, Vs, Aout);
    hipLaunchKernelGGL(gemm_proj, dim3(512), dim3(512), 0, stream, Aout, Wt, out);
}